// Round 5
// baseline (35.778 us; speedup 1.0000x reference)
//
#include <hip/hip_runtime.h>
#include <hip/hip_bf16.h>
#include <math.h>

#define NH 16
#define SL 2048
#define DM 128

typedef float f32x4 __attribute__((ext_vector_type(4)));
typedef short s16x8 __attribute__((ext_vector_type(8)));
typedef short s16x4 __attribute__((ext_vector_type(4)));

static __device__ __forceinline__ short f2bf(float f) {
  __hip_bfloat16 h = __float2bfloat16(f);
  return __builtin_bit_cast(short, h);
}

// ---------------- pre-pass: fp32 K/V -> bf16 swizzled tile chunks in ws ------
// K chunk (h,T): 16KB, element (r,d) at byte (r*256+2d)^((r&7)<<4)  [64 rows]
// V chunk (h,T): 16KB, element (d,k) at byte (d*128+2k)^((d&7)<<4)  [transposed]
__global__ __launch_bounds__(256) void convert_kv(
    const float* __restrict__ kg, const float* __restrict__ vg,
    char* __restrict__ kbf, char* __restrict__ vbf)
{
  const int t = threadIdx.x;
  const int h = blockIdx.x & 15;
  const int T = blockIdx.x >> 4;
  const float* ks = kg + ((size_t)h * SL + (size_t)T * 64) * DM;
  const float* vs = vg + ((size_t)h * SL + (size_t)T * 64) * DM;
  char* kc = kbf + (((size_t)h * 32 + T) << 14);
  char* vc = vbf + (((size_t)h * 32 + T) << 14);
  const int d0 = (t & 31) * 4;
  const int r0 = t >> 5;
  #pragma unroll
  for (int ri = 0; ri < 8; ++ri) {
    int r = r0 + 8 * ri;
    f32x4 f = *(const f32x4*)(ks + (size_t)r * DM + d0);
    s16x4 b;
    b[0] = f2bf(f[0]); b[1] = f2bf(f[1]); b[2] = f2bf(f[2]); b[3] = f2bf(f[3]);
    *(s16x4*)(kc + ((r * 256 + d0 * 2) ^ ((r & 7) << 4))) = b;
  }
  #pragma unroll
  for (int ki = 0; ki < 2; ++ki) {
    int k0 = r0 * 4 + 32 * ki;
    f32x4 a0 = *(const f32x4*)(vs + (size_t)(k0 + 0) * DM + d0);
    f32x4 a1 = *(const f32x4*)(vs + (size_t)(k0 + 1) * DM + d0);
    f32x4 a2 = *(const f32x4*)(vs + (size_t)(k0 + 2) * DM + d0);
    f32x4 a3 = *(const f32x4*)(vs + (size_t)(k0 + 3) * DM + d0);
    #pragma unroll
    for (int dd = 0; dd < 4; ++dd) {
      int d = d0 + dd;
      s16x4 b;
      b[0] = f2bf(a0[dd]); b[1] = f2bf(a1[dd]); b[2] = f2bf(a2[dd]); b[3] = f2bf(a3[dd]);
      *(s16x4*)(vc + ((d * 128 + k0 * 2) ^ ((d & 7) << 4))) = b;
    }
  }
}

// ---------------- main attention: bf16 tiles from ws, dbuf + counted vmcnt ---
#define GLDS16(gsrc, lbase) \
  __builtin_amdgcn_global_load_lds( \
      (const __attribute__((address_space(1))) void*)(gsrc), \
      (__attribute__((address_space(3))) void*)(lbase), 16, 0, 0)

__global__ __launch_bounds__(256) void attn_mfma2(
    const float* __restrict__ qg,
    const char* __restrict__ kbf, const char* __restrict__ vbf,
    const int* __restrict__ offs, int n_off,
    float* __restrict__ out)
{
  __shared__ __align__(16) char Kb[2][16384];
  __shared__ __align__(16) char Vb[2][16384];
  __shared__ __align__(16) char Pb[4][2048];

  const int t    = threadIdx.x;
  const int lane = t & 63;
  const int w    = t >> 6;
  const int col  = lane & 15;
  const int g    = lane >> 4;

  // complementary pairing: block b (z=0, 8-u tiles) + b+256 (z=1, u+1 tiles) = 9
  const int blk = blockIdx.x;
  const int z = blk >> 8;
  const int y = (blk >> 4) & 15;
  const int h = blk & 15;
  const int dno = y >> 2, u = y & 3;
  const int p = z ? u : 7 - u;
  const int q0 = (dno * 8 + p) * 64;

  const float* qh = qg + (size_t)h * SL * DM;
  const float scale = 0.08838834764831843f; // 1/sqrt(128)

  const int qrow = q0 + 16 * w + col;
  int qstart = 0;
  for (int i = 0; i < n_off; ++i) { int o = offs[i]; if (o <= qrow) qstart = o; }
  int kv_lo = 0;
  for (int i = 0; i < n_off; ++i) { int o = offs[i]; if (o <= q0) kv_lo = o; }
  const int ntiles = ((q0 + 64) - kv_lo) >> 6;
  const int T0 = kv_lo >> 6;

  const char* kc = kbf + (((size_t)h * 32) << 14);
  const char* vc = vbf + (((size_t)h * 32) << 14);

#define STAGE(T, B) do {                                                     \
    const char* _ks = kc + (((size_t)(T)) << 14);                            \
    const char* _vs = vc + (((size_t)(T)) << 14);                            \
    _Pragma("unroll")                                                        \
    for (int _i = 0; _i < 4; ++_i) {                                         \
      const int _lo = (w + 4 * _i) << 10;                                    \
      GLDS16(_ks + _lo + lane * 16, &Kb[B][_lo]);                            \
      GLDS16(_vs + _lo + lane * 16, &Vb[B][_lo]);                            \
    }                                                                        \
  } while (0)

  // Q raw loads first so they overlap with the prologue STAGE
  f32x4 qlo[4], qhi[4];
  #pragma unroll
  for (int kk = 0; kk < 4; ++kk) {
    const float* qp = qh + (size_t)qrow * DM + 32 * kk + 8 * g;
    qlo[kk] = *(const f32x4*)qp;
    qhi[kk] = *(const f32x4*)(qp + 4);
  }

  STAGE(T0, 0);

  s16x8 qf[4];
  #pragma unroll
  for (int kk = 0; kk < 4; ++kk) {
    s16x8 f;
    f[0] = f2bf(qlo[kk][0] * scale); f[1] = f2bf(qlo[kk][1] * scale);
    f[2] = f2bf(qlo[kk][2] * scale); f[3] = f2bf(qlo[kk][3] * scale);
    f[4] = f2bf(qhi[kk][0] * scale); f[5] = f2bf(qhi[kk][1] * scale);
    f[6] = f2bf(qhi[kk][2] * scale); f[7] = f2bf(qhi[kk][3] * scale);
    qf[kk] = f;
  }

  f32x4 acc[8];
  #pragma unroll
  for (int dt = 0; dt < 8; ++dt) { f32x4 zv = {0.f, 0.f, 0.f, 0.f}; acc[dt] = zv; }
  float m_ = -1e30f, l_ = 0.f;

  char* pb = &Pb[w][0];
  int buf = 0;

  for (int it = 0; it < ntiles; ++it) {
    const int kv0 = kv_lo + (it << 6);
    if (it + 1 < ntiles) {
      STAGE(T0 + it + 1, buf ^ 1);
      asm volatile("s_waitcnt vmcnt(8)" ::: "memory");
    } else {
      asm volatile("s_waitcnt vmcnt(0)" ::: "memory");
    }
    __builtin_amdgcn_sched_barrier(0);
    __builtin_amdgcn_s_barrier();

    // ---- QK^T (swapped): st[kt] = K_tile_kt . Q^T -> S^T[k][q] ----
    f32x4 st[4];
    #pragma unroll
    for (int kt = 0; kt < 4; ++kt) { f32x4 zv = {0.f, 0.f, 0.f, 0.f}; st[kt] = zv; }
    __builtin_amdgcn_s_setprio(1);
    #pragma unroll
    for (int kt = 0; kt < 4; ++kt) {
      int row = kt * 16 + col;
      #pragma unroll
      for (int kk = 0; kk < 4; ++kk) {
        s16x8 kf = *(const s16x8*)(&Kb[buf][0] + ((row * 256 + 64 * kk + 16 * g) ^ ((row & 7) << 4)));
        st[kt] = __builtin_amdgcn_mfma_f32_16x16x32_bf16(kf, qf[kk], st[kt], 0, 0, 0);
      }
    }
    __builtin_amdgcn_s_setprio(0);

    // ---- online softmax; write P (bf16) to per-wave LDS ----
    float cm = -3.0e38f;
    #pragma unroll
    for (int kt = 0; kt < 4; ++kt) {
      #pragma unroll
      for (int r = 0; r < 4; ++r) {
        int kpos = kv0 + kt * 16 + 4 * g + r;
        float x = st[kt][r];
        bool ok = (kpos <= qrow) && (kpos >= qstart);
        x = ok ? x : -3.0e38f;
        st[kt][r] = x;
        cm = fmaxf(cm, x);
      }
    }
    cm = fmaxf(cm, __shfl_xor(cm, 16));
    cm = fmaxf(cm, __shfl_xor(cm, 32));
    float mn = fmaxf(m_, cm);
    float al = __expf(m_ - mn);
    m_ = mn;
    float psum = 0.f;
    #pragma unroll
    for (int kt = 0; kt < 4; ++kt) {
      s16x4 pk;
      #pragma unroll
      for (int r = 0; r < 4; ++r) {
        float pe = __expf(st[kt][r] - mn);
        psum += pe;
        pk[r] = f2bf(pe);
      }
      *(s16x4*)(pb + ((col * 128 + 32 * kt + 8 * g) ^ ((col & 7) << 4))) = pk;
    }
    psum += __shfl_xor(psum, 16);
    psum += __shfl_xor(psum, 32);
    l_ = l_ * al + psum;

    // ---- rescale O by alpha (per output row 4g+r) ----
    #pragma unroll
    for (int r = 0; r < 4; ++r) {
      float ar = __shfl(al, 4 * g + r);
      #pragma unroll
      for (int dt = 0; dt < 8; ++dt) acc[dt][r] *= ar;
    }

    // cross-lane LDS RAW (same wave): drain P writes before fragment reads
    asm volatile("s_waitcnt lgkmcnt(0)" ::: "memory");
    __builtin_amdgcn_sched_barrier(0);

    // ---- PV: acc[dt] += P . V ----
    __builtin_amdgcn_s_setprio(1);
    #pragma unroll
    for (int ksel = 0; ksel < 2; ++ksel) {
      s16x8 pa = *(const s16x8*)(pb + ((col * 128 + 64 * ksel + 16 * g) ^ ((col & 7) << 4)));
      #pragma unroll
      for (int dt = 0; dt < 8; ++dt) {
        int d = dt * 16 + col;
        s16x8 vf = *(const s16x8*)(&Vb[buf][0] + ((d * 128 + 64 * ksel + 16 * g) ^ ((d & 7) << 4)));
        acc[dt] = __builtin_amdgcn_mfma_f32_16x16x32_bf16(pa, vf, acc[dt], 0, 0, 0);
      }
    }
    __builtin_amdgcn_s_setprio(0);
    __builtin_amdgcn_sched_barrier(0);
    __builtin_amdgcn_s_barrier();
    buf ^= 1;
  }
#undef STAGE

  // ---- epilogue: divide by l, store fp32 ----
  #pragma unroll
  for (int r = 0; r < 4; ++r) {
    float lr  = __shfl(l_, 4 * g + r);
    float inv = 1.f / lr;
    int row   = q0 + 16 * w + 4 * g + r;
    float* op = out + ((size_t)h * SL + row) * DM + col;
    #pragma unroll
    for (int dt = 0; dt < 8; ++dt) op[dt * 16] = acc[dt][r] * inv;
  }
}

// ---------------- fallback (round-4 kernel) if ws is too small ---------------
__global__ __launch_bounds__(256) void attn_mfma_fb(
    const float* __restrict__ qg,
    const float* __restrict__ kg,
    const float* __restrict__ vg,
    const int* __restrict__ offs, int n_off,
    float* __restrict__ out)
{
  __shared__ __align__(16) char Kb[64 * 128 * 2];
  __shared__ __align__(16) char Vb[128 * 64 * 2];
  __shared__ __align__(16) char Pb[4][16 * 64 * 2];

  const int t    = threadIdx.x;
  const int lane = t & 63;
  const int w    = t >> 6;
  const int col  = lane & 15;
  const int g    = lane >> 4;

  const int h  = blockIdx.x & 15;
  const int qb = 31 - (blockIdx.x >> 4);
  const int q0 = qb * 64;

  const float* qh = qg + (size_t)h * SL * DM;
  const float* kh = kg + (size_t)h * SL * DM;
  const float* vh = vg + (size_t)h * SL * DM;

  const float scale = 0.08838834764831843f;

  const int qrow = q0 + 16 * w + col;
  int qstart = 0;
  for (int i = 0; i < n_off; ++i) { int o = offs[i]; if (o <= qrow) qstart = o; }
  int kv_lo = 0;
  for (int i = 0; i < n_off; ++i) { int o = offs[i]; if (o <= q0) kv_lo = o; }

  s16x8 qf[4];
  #pragma unroll
  for (int kk = 0; kk < 4; ++kk) {
    const float* qp = qh + (size_t)qrow * DM + 32 * kk + 8 * g;
    f32x4 lo = *(const f32x4*)qp;
    f32x4 hi = *(const f32x4*)(qp + 4);
    s16x8 f;
    f[0] = f2bf(lo[0] * scale); f[1] = f2bf(lo[1] * scale);
    f[2] = f2bf(lo[2] * scale); f[3] = f2bf(lo[3] * scale);
    f[4] = f2bf(hi[0] * scale); f[5] = f2bf(hi[1] * scale);
    f[6] = f2bf(hi[2] * scale); f[7] = f2bf(hi[3] * scale);
    qf[kk] = f;
  }

  f32x4 acc[8];
  #pragma unroll
  for (int dt = 0; dt < 8; ++dt) { f32x4 zv = {0.f, 0.f, 0.f, 0.f}; acc[dt] = zv; }
  float m_ = -1e30f, l_ = 0.f;
  char* pb = &Pb[w][0];

  for (int kv0 = kv_lo; kv0 < q0 + 64; kv0 += 64) {
    {
      const float* ks = kh + (size_t)kv0 * DM;
      const float* vs = vh + (size_t)kv0 * DM;
      const int d0 = (t & 31) * 4;
      const int r0 = t >> 5;
      #pragma unroll
      for (int ri = 0; ri < 8; ++ri) {
        int r = r0 + 8 * ri;
        f32x4 f = *(const f32x4*)(ks + (size_t)r * DM + d0);
        s16x4 b;
        b[0] = f2bf(f[0]); b[1] = f2bf(f[1]); b[2] = f2bf(f[2]); b[3] = f2bf(f[3]);
        *(s16x4*)(Kb + ((r * 256 + d0 * 2) ^ ((r & 7) << 4))) = b;
      }
      const int rot = (t >> 1) & 3;
      #pragma unroll
      for (int ki = 0; ki < 2; ++ki) {
        int k0 = r0 * 4 + 32 * ki;
        f32x4 a0 = *(const f32x4*)(vs + (size_t)(k0 + 0) * DM + d0);
        f32x4 a1 = *(const f32x4*)(vs + (size_t)(k0 + 1) * DM + d0);
        f32x4 a2 = *(const f32x4*)(vs + (size_t)(k0 + 2) * DM + d0);
        f32x4 a3 = *(const f32x4*)(vs + (size_t)(k0 + 3) * DM + d0);
        #pragma unroll
        for (int di = 0; di < 4; ++di) {
          int dd = (di + rot) & 3;
          int d = d0 + dd;
          s16x4 b;
          b[0] = f2bf(a0[dd]); b[1] = f2bf(a1[dd]); b[2] = f2bf(a2[dd]); b[3] = f2bf(a3[dd]);
          *(s16x4*)(Vb + ((d * 128 + k0 * 2) ^ ((d & 7) << 4))) = b;
        }
      }
    }
    __syncthreads();

    f32x4 st[4];
    #pragma unroll
    for (int kt = 0; kt < 4; ++kt) { f32x4 zv = {0.f, 0.f, 0.f, 0.f}; st[kt] = zv; }
    #pragma unroll
    for (int kt = 0; kt < 4; ++kt) {
      int row = kt * 16 + col;
      #pragma unroll
      for (int kk = 0; kk < 4; ++kk) {
        s16x8 kf = *(const s16x8*)(Kb + ((row * 256 + 64 * kk + 16 * g) ^ ((row & 7) << 4)));
        st[kt] = __builtin_amdgcn_mfma_f32_16x16x32_bf16(kf, qf[kk], st[kt], 0, 0, 0);
      }
    }

    float cm = -3.0e38f;
    #pragma unroll
    for (int kt = 0; kt < 4; ++kt) {
      #pragma unroll
      for (int r = 0; r < 4; ++r) {
        int kpos = kv0 + kt * 16 + 4 * g + r;
        float x = st[kt][r];
        bool ok = (kpos <= qrow) && (kpos >= qstart);
        x = ok ? x : -3.0e38f;
        st[kt][r] = x;
        cm = fmaxf(cm, x);
      }
    }
    cm = fmaxf(cm, __shfl_xor(cm, 16));
    cm = fmaxf(cm, __shfl_xor(cm, 32));
    float mn = fmaxf(m_, cm);
    float al = __expf(m_ - mn);
    m_ = mn;
    float psum = 0.f;
    #pragma unroll
    for (int kt = 0; kt < 4; ++kt) {
      s16x4 pk;
      #pragma unroll
      for (int r = 0; r < 4; ++r) {
        float pe = __expf(st[kt][r] - mn);
        psum += pe;
        pk[r] = f2bf(pe);
      }
      *(s16x4*)(pb + ((col * 128 + 32 * kt + 8 * g) ^ ((col & 7) << 4))) = pk;
    }
    psum += __shfl_xor(psum, 16);
    psum += __shfl_xor(psum, 32);
    l_ = l_ * al + psum;

    #pragma unroll
    for (int r = 0; r < 4; ++r) {
      float ar = __shfl(al, 4 * g + r);
      #pragma unroll
      for (int dt = 0; dt < 8; ++dt) acc[dt][r] *= ar;
    }

    asm volatile("s_waitcnt lgkmcnt(0)" ::: "memory");
    __builtin_amdgcn_sched_barrier(0);

    #pragma unroll
    for (int ksel = 0; ksel < 2; ++ksel) {
      s16x8 pa = *(const s16x8*)(pb + ((col * 128 + 64 * ksel + 16 * g) ^ ((col & 7) << 4)));
      #pragma unroll
      for (int dt = 0; dt < 8; ++dt) {
        int d = dt * 16 + col;
        s16x8 vf = *(const s16x8*)(Vb + ((d * 128 + 64 * ksel + 16 * g) ^ ((d & 7) << 4)));
        acc[dt] = __builtin_amdgcn_mfma_f32_16x16x32_bf16(pa, vf, acc[dt], 0, 0, 0);
      }
    }
    __syncthreads();
  }

  #pragma unroll
  for (int r = 0; r < 4; ++r) {
    float lr  = __shfl(l_, 4 * g + r);
    float inv = 1.f / lr;
    int row   = q0 + 16 * w + 4 * g + r;
    float* op = out + ((size_t)h * SL + row) * DM + col;
    #pragma unroll
    for (int dt = 0; dt < 8; ++dt) op[dt * 16] = acc[dt][r] * inv;
  }
}

extern "C" void kernel_launch(void* const* d_in, const int* in_sizes, int n_in,
                              void* d_out, int out_size, void* d_ws, size_t ws_size,
                              hipStream_t stream) {
  const float* q = (const float*)d_in[0];
  const float* k = (const float*)d_in[1];
  const float* v = (const float*)d_in[2];
  const int* offs = (const int*)d_in[3];
  const int n_off = in_sizes[3];
  float* out = (float*)d_out;

  const size_t chunk_bytes = (size_t)NH * 32 * 16384; // 8 MB per tensor
  if (ws_size >= 2 * chunk_bytes) {
    char* kbf = (char*)d_ws;
    char* vbf = kbf + chunk_bytes;
    convert_kv<<<NH * 32, 256, 0, stream>>>(k, v, kbf, vbf);
    attn_mfma2<<<512, 256, 0, stream>>>(q, kbf, vbf, offs, n_off, out);
  } else {
    attn_mfma_fb<<<512, 256, 0, stream>>>(q, k, v, offs, n_off, out);
  }
}